// Round 1
// baseline (116.073 us; speedup 1.0000x reference)
//
#include <hip/hip_runtime.h>

// Always (STL "always" operator with smoothed min, window=16) over [B,T,D]
// lower/upper traces, fp32.
//
// Math: out[b,t,d] = -log( sum_{j=0..15} exp(-5 * x[b, max(t-15+j,0), d]) ) / 5
// (h0 = broadcast of x[:,0,:] is exactly clamp-to-0 left padding.)
//
// Strategy: van Herk blocked prefix/suffix sums over 16-aligned blocks ->
// 1 exp + 1 log + ~4 adds per output instead of 16 exps. Memory-bound.
// lane = d (D=64 = wavefront): every global access is a fully coalesced
// 256B dword transaction; each lane is an independent time series so no
// cross-lane communication is needed.

#define TT   8192
#define DD   64
#define BB   16
#define LCH  64   // t-chunk length per wave (16-element clamped halo)

__global__ __launch_bounds__(256) void always_minish_kernel(
    const float* __restrict__ lower,
    const float* __restrict__ upper,
    float* __restrict__ out)
{
    const int lane = threadIdx.x & 63;
    const int wave = threadIdx.x >> 6;
    const int c    = blockIdx.x * 4 + wave;        // global chunk id

    const int chunks_per_seq = TT / LCH;           // 128
    const int seq   = c / chunks_per_seq;          // 0..31  (trace*16 + b)
    const int chunk = c % chunks_per_seq;
    const int tr    = seq >> 4;                    // 0 = lower, 1 = upper
    const int b     = seq & 15;
    const int t0    = chunk * LCH;

    const float* __restrict__ xin =
        (tr ? upper : lower) + (size_t)b * TT * DD + lane;
    float* __restrict__ yout =
        out + (size_t)tr * ((size_t)BB * TT * DD) + (size_t)b * TT * DD + lane;

    const float NSCALE = -5.0f;

    // Suffix sums of the 16 elements preceding t0 (clamped to t=0; for the
    // first chunk this reproduces the h0 = broadcast(x0) padding exactly).
    float s[16];
    {
        float e[16];
        #pragma unroll
        for (int j = 0; j < 16; ++j) {
            int t = t0 - 16 + j;
            if (t < 0) t = 0;
            e[j] = __expf(NSCALE * xin[(size_t)t * DD]);
        }
        s[15] = e[15];
        #pragma unroll
        for (int j = 14; j >= 0; --j) s[j] = e[j] + s[j + 1];
    }

    #pragma unroll
    for (int blk = 0; blk < LCH / 16; ++blk) {
        const int tb = t0 + blk * 16;

        // One exp per element for this aligned 16-block.
        float f[16];
        #pragma unroll
        for (int k = 0; k < 16; ++k)
            f[k] = __expf(NSCALE * xin[(size_t)(tb + k) * DD]);

        // Window sum for t = tb+k over [t-15, t]:
        //   k < 15 : suffix of previous block from k+1  +  prefix of this block
        //   k == 15: whole current block
        float p = 0.0f;
        #pragma unroll
        for (int k = 0; k < 16; ++k) {
            p += f[k];
            const float w = (k < 15) ? (s[k + 1] + p) : p;
            yout[(size_t)(tb + k) * DD] = -0.2f * __logf(w);
        }

        // Suffix sums of this block become "previous block" for the next one.
        s[15] = f[15];
        #pragma unroll
        for (int j = 14; j >= 0; --j) s[j] = f[j] + s[j + 1];
    }
}

extern "C" void kernel_launch(void* const* d_in, const int* in_sizes, int n_in,
                              void* d_out, int out_size, void* d_ws, size_t ws_size,
                              hipStream_t stream)
{
    const float* lower = (const float*)d_in[0];
    const float* upper = (const float*)d_in[1];
    float* out = (float*)d_out;

    // total chunks = 2 traces * 16 b * (8192/64) = 4096 waves = 1024 blocks
    const int total_chunks = 2 * BB * (TT / LCH);
    dim3 grid(total_chunks / 4), block(256);
    hipLaunchKernelGGL(always_minish_kernel, grid, block, 0, stream,
                       lower, upper, out);
}